// Round 2
// baseline (554.650 us; speedup 1.0000x reference)
//
#include <hip/hip_runtime.h>
#include <hip/hip_bf16.h>

#define MQ 65536
#define NKEY 65536
#define KNB 16
#define CCH 64
#define TPB 4   // tiles (of 16 queries) per cross_attn block

typedef _Float16 half8  __attribute__((ext_vector_type(8)));
typedef _Float16 half4v __attribute__((ext_vector_type(4)));
typedef float    floatx4 __attribute__((ext_vector_type(4)));

// ws layout:
//   qp_h [MQ*64] f16, kp_h [NKEY*64] f16, res_g [MQ*64] f16,
//   w4 [4*64*72] f16 (Wg1T,Wg2T,WvT,WtT; transposed, row stride 72),
//   mask_packed [MQ] u16, mflag int

// ---------------- mask dtype detect (1 block) ----------------
__global__ void detect_mask(const unsigned char* __restrict__ m, int* __restrict__ flag)
{
    __shared__ int sflags;
    if (threadIdx.x == 0) sflags = 0;
    __syncthreads();
    const uint4* m4 = (const uint4*)m;
    unsigned int orw = 0;
    #pragma unroll
    for (int it = 0; it < 4; ++it) {
        uint4 v = m4[threadIdx.x + it * 256];
        orw |= v.x | v.y | v.z | v.w;
    }
    int local = 0;
    if (orw & 0x000000FFu) local |= 1;
    if (orw & 0x0000FF00u) local |= 2;
    if (orw & 0xFFFF0000u) local |= 4;
    if (local) atomicOr(&sflags, local);
    __syncthreads();
    if (threadIdx.x == 0) *flag = sflags;
}

// ---------------- proj + mask-pack + weight conversion ----------------
__global__ __launch_bounds__(256, 4)
void proj_prep(const float* __restrict__ q, const float* __restrict__ qpos,
               const float* __restrict__ k, const float* __restrict__ kpos,
               const float* __restrict__ Wqk, const float* __restrict__ bqk,
               const float* __restrict__ Wg1, const float* __restrict__ Wg2,
               const float* __restrict__ Wv,  const float* __restrict__ Wt,
               const unsigned char* __restrict__ maskraw, const int* __restrict__ mflag,
               _Float16* __restrict__ qp_h, _Float16* __restrict__ kp_h,
               _Float16* __restrict__ w4, unsigned short* __restrict__ mask_packed)
{
    const int tid = threadIdx.x;
    const int bid = blockIdx.x;

    if (bid >= 1024) {
        if (bid < 1088) {
            const int mode = *mflag;
            const int qq0 = (bid - 1024) * 1024 + tid * 4;
            unsigned short mp[4];
            #pragma unroll
            for (int i = 0; i < 4; ++i) {
                const int qq = qq0 + i;
                unsigned bits = 0;
                if (mode & 2) {
                    uint4 v = ((const uint4*)maskraw)[qq];
                    unsigned wds[4] = {v.x, v.y, v.z, v.w};
                    #pragma unroll
                    for (int wi = 0; wi < 4; ++wi)
                        #pragma unroll
                        for (int b = 0; b < 4; ++b)
                            if ((wds[wi] >> (8 * b)) & 0xFFu) bits |= 1u << (wi * 4 + b);
                } else {
                    const uint4* p = (const uint4*)maskraw + (size_t)qq * 4;
                    #pragma unroll
                    for (int wi = 0; wi < 4; ++wi) {
                        uint4 v = p[wi];
                        bits |= (v.x ? 1u : 0u) << (wi * 4 + 0);
                        bits |= (v.y ? 1u : 0u) << (wi * 4 + 1);
                        bits |= (v.z ? 1u : 0u) << (wi * 4 + 2);
                        bits |= (v.w ? 1u : 0u) << (wi * 4 + 3);
                    }
                }
                mp[i] = (unsigned short)bits;
            }
            ushort4 o4; o4.x = mp[0]; o4.y = mp[1]; o4.z = mp[2]; o4.w = mp[3];
            *(ushort4*)&mask_packed[qq0] = o4;
        } else {
            const float* Ws[4] = {Wg1, Wg2, Wv, Wt};
            #pragma unroll
            for (int mat = 0; mat < 4; ++mat) {
                const float* W = Ws[mat];
                _Float16* dst = w4 + mat * 64 * 72;
                for (int i = tid; i < 4096; i += 256) {
                    int rr = i >> 6, c = i & 63;
                    dst[c * 72 + rr] = (_Float16)W[i];
                }
            }
        }
        return;
    }

    __shared__ __align__(16) _Float16 A_s[128 * 72];
    __shared__ __align__(16) _Float16 WT_s[64 * 72];

    const int r0 = bid * 128;
    const float* x; const float* p; _Float16* o; int rb;
    if (r0 < MQ) { x = q; p = qpos; o = qp_h; rb = r0; }
    else         { x = k; p = kpos; o = kp_h; rb = r0 - MQ; }

    #pragma unroll
    for (int j = 0; j < 4; ++j) {
        int i = (tid + j * 256) * 4;
        int rr = i >> 6, c4 = i & 63;
        floatx4 wv = *(const floatx4*)&Wqk[i];
        WT_s[(c4 + 0) * 72 + rr] = (_Float16)wv.x;
        WT_s[(c4 + 1) * 72 + rr] = (_Float16)wv.y;
        WT_s[(c4 + 2) * 72 + rr] = (_Float16)wv.z;
        WT_s[(c4 + 3) * 72 + rr] = (_Float16)wv.w;
    }
    #pragma unroll
    for (int j = 0; j < 8; ++j) {
        int flat = tid + j * 256;
        int rr = flat >> 4, c4 = (flat & 15) * 4;
        size_t g = (size_t)(rb + rr) * 64 + c4;
        floatx4 xv = *(const floatx4*)&x[g];
        floatx4 pv = *(const floatx4*)&p[g];
        half4v h;
        h[0] = (_Float16)(xv.x + pv.x); h[1] = (_Float16)(xv.y + pv.y);
        h[2] = (_Float16)(xv.z + pv.z); h[3] = (_Float16)(xv.w + pv.w);
        *(half4v*)&A_s[rr * 72 + c4] = h;
    }
    __syncthreads();

    const int w = tid >> 6, lane = tid & 63, m = lane & 15, qd = lane >> 4;
    const floatx4 fz = {0.f, 0.f, 0.f, 0.f};
    floatx4 acc[2][4];
    #pragma unroll
    for (int rt = 0; rt < 2; rt++)
        #pragma unroll
        for (int ct = 0; ct < 4; ct++) acc[rt][ct] = fz;

    #pragma unroll
    for (int kc = 0; kc < 2; ++kc) {
        const int k0 = kc * 32 + qd * 8;
        half8 b[4];
        #pragma unroll
        for (int ct = 0; ct < 4; ++ct)
            b[ct] = *(const half8*)&WT_s[(ct * 16 + m) * 72 + k0];
        #pragma unroll
        for (int rt = 0; rt < 2; ++rt) {
            half8 a = *(const half8*)&A_s[(w * 32 + rt * 16 + m) * 72 + k0];
            #pragma unroll
            for (int ct = 0; ct < 4; ++ct)
                acc[rt][ct] = __builtin_amdgcn_mfma_f32_16x16x32_f16(a, b[ct], acc[rt][ct], 0, 0, 0);
        }
    }
    #pragma unroll
    for (int rt = 0; rt < 2; rt++)
        #pragma unroll
        for (int ct = 0; ct < 4; ct++) {
            const int col = ct * 16 + m;
            const float bb = bqk[col];
            #pragma unroll
            for (int rg = 0; rg < 4; ++rg) {
                const int row = w * 32 + rt * 16 + qd * 4 + rg;
                A_s[row * 72 + col] = (_Float16)(acc[rt][ct][rg] + bb);
            }
        }
    __syncthreads();
    #pragma unroll
    for (int j = 0; j < 4; ++j) {
        int ch = tid + j * 256;
        int rr = ch >> 3, off = (ch & 7) * 8;
        *(half8*)&o[(size_t)(rb + rr) * 64 + off] = *(const half8*)&A_s[rr * 72 + off];
    }
}

// ---------------- persistent fused edge-MLP + softmax + aggregate ----------------
// LDS 46080 B -> 3 blocks/CU; waves_per_eu(3,3) pins VGPR <= 168 so 12 waves/CU fly.
// Register diet: vraw pair-granular (32 regs), qpr pair-local (8), v packed f16 (16).
// Math: bg2 dropped (softmax-invariant along neighbor axis); bv folded post-norm.
__global__ __launch_bounds__(256) __attribute__((amdgpu_waves_per_eu(3, 3)))
void cross_attn(const float* __restrict__ value, const unsigned short* __restrict__ mask_packed,
                const int* __restrict__ idx,
                const _Float16* __restrict__ qp_h, const _Float16* __restrict__ kp_h,
                const _Float16* __restrict__ w4,
                const float* __restrict__ bg1, const float* __restrict__ bv,
                _Float16* __restrict__ res_g)
{
    __shared__ __align__(16) _Float16 W3_s[3 * 64 * 72];  // Wg1T, Wg2T, WvT
    __shared__ __align__(16) _Float16 H_s[128 * 72];      // wave-private 32-row regions

    const int tid = threadIdx.x, w = tid >> 6, lane = tid & 63, m = lane & 15, qd = (lane >> 4) & 3;
    const int tile0 = blockIdx.x * TPB;

    for (int ch = tid; ch < 1728; ch += 256)
        *(half8*)&W3_s[ch * 8] = *(const half8*)&w4[ch * 8];

    float bg1v[4];
    #pragma unroll
    for (int ct = 0; ct < 4; ct++) bg1v[ct] = bg1[ct * 16 + m];
    const float bvsel = bv[lane];   // res col == lane; sum(attn)==1 -> bv adds post-norm

    // ---- prologue: tile-0 idx/mask/qp(pair0)/value(pair0) ----
    int idxn[4];
    uint2 mpr;
    half8 qpr[2][2];      // current pair's qp rows
    half8 kpr[4][2];      // whole tile's gathered kp rows
    floatx4 vraw[8];      // one pair (2 query rows) of raw value
    {
        const int q0 = tile0 * 16;
        mpr = *(const uint2*)&mask_packed[q0 + w * 4];
        #pragma unroll
        for (int rt = 0; rt < 4; ++rt)
            idxn[rt] = idx[(q0 + w * 4 + rt) * KNB + m];
        #pragma unroll
        for (int rr = 0; rr < 2; ++rr)
            #pragma unroll
            for (int kc = 0; kc < 2; ++kc)
                qpr[rr][kc] = *(const half8*)&qp_h[(size_t)(q0 + w * 4 + rr) * 64 + kc * 32 + qd * 8];
        #pragma unroll
        for (int rr = 0; rr < 2; ++rr)
            #pragma unroll
            for (int kc = 0; kc < 2; ++kc) {
                const float* vr = value + ((size_t)(q0 + w * 4 + rr) * KNB + m) * 64 + kc * 32 + qd * 8;
                vraw[(rr * 2 + kc) * 2 + 0] = *(const floatx4*)vr;
                vraw[(rr * 2 + kc) * 2 + 1] = *(const floatx4*)(vr + 4);
            }
    }
    __syncthreads();   // weights ready; ONLY barrier

    const _Float16* Wg1T = W3_s;
    const _Float16* Wg2T = W3_s + 4608;
    const _Float16* WvT  = W3_s + 2 * 4608;
    const floatx4 fz = {0.f, 0.f, 0.f, 0.f};

    for (int t = 0; t < TPB; ++t) {
        const int q0t = (tile0 + t) * 16;
        const bool more = (t + 1 < TPB);

        const uint2 mcur = mpr;

        // ---- kp gather for all 4 queries (idx prefetched last tile) ----
        #pragma unroll
        for (int rt = 0; rt < 4; ++rt)
            #pragma unroll
            for (int kc = 0; kc < 2; ++kc)
                kpr[rt][kc] = *(const half8*)&kp_h[(size_t)idxn[rt] * 64 + kc * 32 + qd * 8];

        #pragma unroll
        for (int pr = 0; pr < 2; ++pr) {
            const int r0 = pr * 2;

            // value frags for this pair (vraw prefetched one pair-phase ago)
            half8 vfrag[2][2];
            #pragma unroll
            for (int rr = 0; rr < 2; ++rr)
                #pragma unroll
                for (int kc = 0; kc < 2; ++kc) {
                    floatx4 x0 = vraw[(rr * 2 + kc) * 2 + 0];
                    floatx4 x1 = vraw[(rr * 2 + kc) * 2 + 1];
                    half8 a;
                    #pragma unroll
                    for (int j = 0; j < 4; ++j) { a[j] = (_Float16)x0[j]; a[4 + j] = (_Float16)x1[j]; }
                    vfrag[rr][kc] = a;
                }

            // refill vraw: pair1 of this tile (pr==0, always) / pair0 of next tile (pr==1, if more)
            if (pr == 0 || more) {
                const int qb = (pr == 0) ? (q0t + 2) : (q0t + 16);
                #pragma unroll
                for (int rr = 0; rr < 2; ++rr) {
                    const float* vr = value + ((size_t)(qb + w * 4 + rr) * KNB + m) * 64 + qd * 8;
                    vraw[(rr * 2 + 0) * 2 + 0] = *(const floatx4*)vr;
                    vraw[(rr * 2 + 0) * 2 + 1] = *(const floatx4*)(vr + 4);
                    vraw[(rr * 2 + 1) * 2 + 0] = *(const floatx4*)(vr + 32);
                    vraw[(rr * 2 + 1) * 2 + 1] = *(const floatx4*)(vr + 36);
                }
            }

            // v = value @ Wv for pair (no bias; bv folded post-norm), pack to f16
            half4v vh[2][4];
            {
                floatx4 accv[2][4];
                #pragma unroll
                for (int rr = 0; rr < 2; ++rr)
                    #pragma unroll
                    for (int ct = 0; ct < 4; ++ct) accv[rr][ct] = fz;
                #pragma unroll
                for (int kc = 0; kc < 2; ++kc) {
                    const int k0 = kc * 32 + qd * 8;
                    half8 b[4];
                    #pragma unroll
                    for (int ct = 0; ct < 4; ++ct)
                        b[ct] = *(const half8*)&WvT[(ct * 16 + m) * 72 + k0];
                    #pragma unroll
                    for (int rr = 0; rr < 2; ++rr)
                        #pragma unroll
                        for (int ct = 0; ct < 4; ++ct)
                            accv[rr][ct] = __builtin_amdgcn_mfma_f32_16x16x32_f16(vfrag[rr][kc], b[ct], accv[rr][ct], 0, 0, 0);
                }
                #pragma unroll
                for (int rr = 0; rr < 2; ++rr)
                    #pragma unroll
                    for (int ct = 0; ct < 4; ++ct) {
                        half4v hv;
                        #pragma unroll
                        for (int rg = 0; rg < 4; ++rg) hv[rg] = (_Float16)accv[rr][ct][rg];
                        vh[rr][ct] = hv;
                    }
            }

            // h = relu(d @ Wg1 + bg1), d-frags in registers
            floatx4 acch[2][4];
            #pragma unroll
            for (int rr = 0; rr < 2; ++rr)
                #pragma unroll
                for (int ct = 0; ct < 4; ++ct) acch[rr][ct] = fz;
            #pragma unroll
            for (int kc = 0; kc < 2; ++kc) {
                const int k0 = kc * 32 + qd * 8;
                half8 b[4];
                #pragma unroll
                for (int ct = 0; ct < 4; ++ct)
                    b[ct] = *(const half8*)&Wg1T[(ct * 16 + m) * 72 + k0];
                #pragma unroll
                for (int rr = 0; rr < 2; ++rr) {
                    half8 a = qpr[rr][kc] - kpr[r0 + rr][kc];
                    #pragma unroll
                    for (int ct = 0; ct < 4; ++ct)
                        acch[rr][ct] = __builtin_amdgcn_mfma_f32_16x16x32_f16(a, b[ct], acch[rr][ct], 0, 0, 0);
                }
            }

            // qpr dead after Wg1 -> load pair1(t) / pair0(t+1)
            if (pr == 0 || more) {
                const int qb = (pr == 0) ? (q0t + 2) : (q0t + 16);
                #pragma unroll
                for (int rr = 0; rr < 2; ++rr)
                    #pragma unroll
                    for (int kc = 0; kc < 2; ++kc)
                        qpr[rr][kc] = *(const half8*)&qp_h[(size_t)(qb + w * 4 + rr) * 64 + kc * 32 + qd * 8];
            }

            // h -> wave-private LDS (32 rows per wave; pairs reuse sequentially)
            #pragma unroll
            for (int rr = 0; rr < 2; ++rr)
                #pragma unroll
                for (int ct = 0; ct < 4; ++ct) {
                    const int col = ct * 16 + m;
                    #pragma unroll
                    for (int rg = 0; rg < 4; ++rg) {
                        const int row = w * 32 + rr * 16 + qd * 4 + rg;
                        float h = acch[rr][ct][rg] + bg1v[ct];
                        H_s[row * 72 + col] = (_Float16)fmaxf(h, 0.f);
                    }
                }
            __asm__ volatile("s_waitcnt lgkmcnt(0)" ::: "memory");

            // e = h @ Wg2 (bg2 dropped: uniform along softmax axis)
            floatx4 acce[2][4];
            #pragma unroll
            for (int rr = 0; rr < 2; ++rr)
                #pragma unroll
                for (int ct = 0; ct < 4; ++ct) acce[rr][ct] = fz;
            #pragma unroll
            for (int kc = 0; kc < 2; ++kc) {
                const int k0 = kc * 32 + qd * 8;
                half8 b[4];
                #pragma unroll
                for (int ct = 0; ct < 4; ++ct)
                    b[ct] = *(const half8*)&Wg2T[(ct * 16 + m) * 72 + k0];
                #pragma unroll
                for (int rr = 0; rr < 2; ++rr) {
                    half8 a = *(const half8*)&H_s[(w * 32 + rr * 16 + m) * 72 + k0];
                    #pragma unroll
                    for (int ct = 0; ct < 4; ++ct)
                        acce[rr][ct] = __builtin_amdgcn_mfma_f32_16x16x32_f16(a, b[ct], acce[rr][ct], 0, 0, 0);
                }
            }

            // after pair 0: prefetch next tile's idx + mask (consumed next tile top)
            if (pr == 0 && more) {
                const int q0n = q0t + 16;
                mpr = *(const uint2*)&mask_packed[q0n + w * 4];
                #pragma unroll
                for (int rt = 0; rt < 4; ++rt)
                    idxn[rt] = idx[(q0n + w * 4 + rt) * KNB + m];
            }

            // softmax over 16 neighbors (rows) + aggregate; sum & weighted-sum fused reduce
            const unsigned mword = (pr == 0) ? mcur.x : mcur.y;
            #pragma unroll
            for (int rr = 0; rr < 2; ++rr) {
                const int sh = rr * 16 + qd * 4;
                float tca[4];
                #pragma unroll
                for (int ct = 0; ct < 4; ++ct) {
                    float ev[4];
                    #pragma unroll
                    for (int rg = 0; rg < 4; ++rg) {
                        float e = acce[rr][ct][rg];
                        ev[rg] = ((mword >> (sh + rg)) & 1u) ? -1e12f : e;
                    }
                    float mx = fmaxf(fmaxf(ev[0], ev[1]), fmaxf(ev[2], ev[3]));
                    mx = fmaxf(mx, __shfl_xor(mx, 16));
                    mx = fmaxf(mx, __shfl_xor(mx, 32));
                    float s = 0.f, ttu = 0.f;
                    #pragma unroll
                    for (int rg = 0; rg < 4; ++rg) {
                        float p = __expf(ev[rg] - mx);
                        s += p; ttu += p * (float)vh[rr][ct][rg];
                    }
                    s   += __shfl_xor(s, 16);   ttu += __shfl_xor(ttu, 16);
                    s   += __shfl_xor(s, 32);   ttu += __shfl_xor(ttu, 32);
                    tca[ct] = ttu * __builtin_amdgcn_rcpf(s);
                }
                float tsel = (qd == 0) ? tca[0] : (qd == 1) ? tca[1] : (qd == 2) ? tca[2] : tca[3];
                res_g[(size_t)(q0t + w * 4 + r0 + rr) * 64 + lane] = (_Float16)(tsel + bvsel);
            }
        }
    }
}

// ---------------- out = res @ Wt + bt ----------------
__global__ __launch_bounds__(256, 4)
void out_proj(const _Float16* __restrict__ res_g, const _Float16* __restrict__ w4,
              const float* __restrict__ bt, float* __restrict__ out)
{
    __shared__ __align__(16) _Float16 WtT_s[64 * 72];
    const int tid = threadIdx.x;
    const _Float16* WtT_g = w4 + 3 * 4608;
    for (int ch = tid; ch < 576; ch += 256)
        *(half8*)&WtT_s[ch * 8] = *(const half8*)&WtT_g[ch * 8];
    __syncthreads();

    const int w = tid >> 6, lane = tid & 63, m = lane & 15, qd = lane >> 4;
    const int rb = blockIdx.x * 256;
    const floatx4 fz = {0.f, 0.f, 0.f, 0.f};
    float btv[4];
    #pragma unroll
    for (int ct = 0; ct < 4; ++ct) btv[ct] = bt[ct * 16 + m];

    #pragma unroll
    for (int rt = 0; rt < 4; ++rt) {
        floatx4 acc[4] = {fz, fz, fz, fz};
        #pragma unroll
        for (int kc = 0; kc < 2; ++kc) {
            const int k0 = kc * 32 + qd * 8;
            half8 a = *(const half8*)&res_g[(size_t)(rb + w * 64 + rt * 16 + m) * 64 + k0];
            half8 b[4];
            #pragma unroll
            for (int ct = 0; ct < 4; ++ct)
                b[ct] = *(const half8*)&WtT_s[(ct * 16 + m) * 72 + k0];
            #pragma unroll
            for (int ct = 0; ct < 4; ++ct)
                acc[ct] = __builtin_amdgcn_mfma_f32_16x16x32_f16(a, b[ct], acc[ct], 0, 0, 0);
        }
        #pragma unroll
        for (int ct = 0; ct < 4; ++ct) {
            #pragma unroll
            for (int rg = 0; rg < 4; ++rg)
                out[(size_t)(rb + w * 64 + rt * 16 + qd * 4 + rg) * 64 + ct * 16 + m] = acc[ct][rg] + btv[ct];
        }
    }
}

extern "C" void kernel_launch(void* const* d_in, const int* in_sizes, int n_in,
                              void* d_out, int out_size, void* d_ws, size_t ws_size,
                              hipStream_t stream) {
    const float* q     = (const float*)d_in[0];
    const float* k     = (const float*)d_in[1];
    const float* value = (const float*)d_in[2];
    const float* q_pos = (const float*)d_in[3];
    const float* k_pos = (const float*)d_in[4];
    const unsigned char* mask = (const unsigned char*)d_in[5];
    const int* knn     = (const int*)d_in[6];
    // d_in[7] = k_num scalar (16)
    const float* Wqk = (const float*)d_in[8];
    const float* bqk = (const float*)d_in[9];
    const float* Wv  = (const float*)d_in[10];
    const float* bv  = (const float*)d_in[11];
    const float* Wg1 = (const float*)d_in[12];
    const float* bg1 = (const float*)d_in[13];
    const float* Wg2 = (const float*)d_in[14];
    const float* bg2 = (const float*)d_in[15];
    const float* Wt  = (const float*)d_in[16];
    const float* bt  = (const float*)d_in[17];
    float* out = (float*)d_out;
    (void)bg2;   // softmax-invariant: dropped

    _Float16* qp_h  = (_Float16*)d_ws;
    _Float16* kp_h  = qp_h + (size_t)MQ * CCH;
    _Float16* res_g = kp_h + (size_t)NKEY * CCH;
    _Float16* w4    = res_g + (size_t)MQ * CCH;
    unsigned short* mask_packed = (unsigned short*)(w4 + 4 * 64 * 72);
    int* mflag = (int*)(mask_packed + MQ);
    const int* idx = knn + (size_t)MQ * KNB;   // row 1 of knearest_idx

    detect_mask<<<1, 256, 0, stream>>>(mask, mflag);
    proj_prep<<<1089, 256, 0, stream>>>(q, q_pos, k, k_pos, Wqk, bqk,
                                        Wg1, Wg2, Wv, Wt, mask, mflag,
                                        qp_h, kp_h, w4, mask_packed);
    cross_attn<<<MQ / (16 * TPB), 256, 0, stream>>>(value, mask_packed, idx, qp_h, kp_h, w4,
                                                    bg1, bv, res_g);
    out_proj<<<MQ / 256, 256, 0, stream>>>(res_g, w4, bt, out);
}

// Round 3
// 523.405 us; speedup vs baseline: 1.0597x; 1.0597x over previous
//
#include <hip/hip_runtime.h>
#include <hip/hip_bf16.h>

#define MQ 65536
#define NKEY 65536
#define KNB 16
#define CCH 64
#define TPB 8   // tiles (of 16 queries) per cross_attn block

typedef _Float16 half8  __attribute__((ext_vector_type(8)));
typedef _Float16 half4v __attribute__((ext_vector_type(4)));
typedef float    floatx4 __attribute__((ext_vector_type(4)));

#if __has_builtin(__builtin_amdgcn_exp2f)
#define EXP2F(x) __builtin_amdgcn_exp2f(x)
#else
#define EXP2F(x) exp2f(x)
#endif

// ws layout:
//   qp_h [MQ*64] f16, kp_h [NKEY*64] f16, res_g [MQ*64] f16,
//   w4 [4*64*72] f16 (Wg1T,Wg2T(*log2e),WvT,WtT; transposed, row stride 72),
//   mask_packed [MQ] u16, mflag int

// ---------------- mask dtype detect (1 block) ----------------
__global__ void detect_mask(const unsigned char* __restrict__ m, int* __restrict__ flag)
{
    __shared__ int sflags;
    if (threadIdx.x == 0) sflags = 0;
    __syncthreads();
    const uint4* m4 = (const uint4*)m;
    unsigned int orw = 0;
    #pragma unroll
    for (int it = 0; it < 4; ++it) {
        uint4 v = m4[threadIdx.x + it * 256];
        orw |= v.x | v.y | v.z | v.w;
    }
    int local = 0;
    if (orw & 0x000000FFu) local |= 1;
    if (orw & 0x0000FF00u) local |= 2;
    if (orw & 0xFFFF0000u) local |= 4;
    if (local) atomicOr(&sflags, local);
    __syncthreads();
    if (threadIdx.x == 0) *flag = sflags;
}

// ---------------- proj + mask-pack + weight conversion ----------------
__global__ __launch_bounds__(256, 4)
void proj_prep(const float* __restrict__ q, const float* __restrict__ qpos,
               const float* __restrict__ k, const float* __restrict__ kpos,
               const float* __restrict__ Wqk, const float* __restrict__ bqk,
               const float* __restrict__ Wg1, const float* __restrict__ Wg2,
               const float* __restrict__ Wv,  const float* __restrict__ Wt,
               const unsigned char* __restrict__ maskraw, const int* __restrict__ mflag,
               _Float16* __restrict__ qp_h, _Float16* __restrict__ kp_h,
               _Float16* __restrict__ w4, unsigned short* __restrict__ mask_packed)
{
    const int tid = threadIdx.x;
    const int bid = blockIdx.x;

    if (bid >= 1024) {
        if (bid < 1088) {
            const int mode = *mflag;
            const int qq0 = (bid - 1024) * 1024 + tid * 4;
            unsigned short mp[4];
            #pragma unroll
            for (int i = 0; i < 4; ++i) {
                const int qq = qq0 + i;
                unsigned bits = 0;
                if (mode & 2) {
                    uint4 v = ((const uint4*)maskraw)[qq];
                    unsigned wds[4] = {v.x, v.y, v.z, v.w};
                    #pragma unroll
                    for (int wi = 0; wi < 4; ++wi)
                        #pragma unroll
                        for (int b = 0; b < 4; ++b)
                            if ((wds[wi] >> (8 * b)) & 0xFFu) bits |= 1u << (wi * 4 + b);
                } else {
                    const uint4* p = (const uint4*)maskraw + (size_t)qq * 4;
                    #pragma unroll
                    for (int wi = 0; wi < 4; ++wi) {
                        uint4 v = p[wi];
                        bits |= (v.x ? 1u : 0u) << (wi * 4 + 0);
                        bits |= (v.y ? 1u : 0u) << (wi * 4 + 1);
                        bits |= (v.z ? 1u : 0u) << (wi * 4 + 2);
                        bits |= (v.w ? 1u : 0u) << (wi * 4 + 3);
                    }
                }
                mp[i] = (unsigned short)bits;
            }
            ushort4 o4; o4.x = mp[0]; o4.y = mp[1]; o4.z = mp[2]; o4.w = mp[3];
            *(ushort4*)&mask_packed[qq0] = o4;
        } else {
            const float* Ws[4] = {Wg1, Wg2, Wv, Wt};
            #pragma unroll
            for (int mat = 0; mat < 4; ++mat) {
                const float* W = Ws[mat];
                const float sc = (mat == 1) ? 1.44269504f : 1.0f;  // Wg2 pre-scaled by log2(e): softmax via raw v_exp_f32
                _Float16* dst = w4 + mat * 64 * 72;
                for (int i = tid; i < 4096; i += 256) {
                    int rr = i >> 6, c = i & 63;
                    dst[c * 72 + rr] = (_Float16)(W[i] * sc);
                }
            }
        }
        return;
    }

    __shared__ __align__(16) _Float16 A_s[128 * 72];
    __shared__ __align__(16) _Float16 WT_s[64 * 72];

    const int r0 = bid * 128;
    const float* x; const float* p; _Float16* o; int rb;
    if (r0 < MQ) { x = q; p = qpos; o = qp_h; rb = r0; }
    else         { x = k; p = kpos; o = kp_h; rb = r0 - MQ; }

    #pragma unroll
    for (int j = 0; j < 4; ++j) {
        int i = (tid + j * 256) * 4;
        int rr = i >> 6, c4 = i & 63;
        floatx4 wv = *(const floatx4*)&Wqk[i];
        WT_s[(c4 + 0) * 72 + rr] = (_Float16)wv.x;
        WT_s[(c4 + 1) * 72 + rr] = (_Float16)wv.y;
        WT_s[(c4 + 2) * 72 + rr] = (_Float16)wv.z;
        WT_s[(c4 + 3) * 72 + rr] = (_Float16)wv.w;
    }
    #pragma unroll
    for (int j = 0; j < 8; ++j) {
        int flat = tid + j * 256;
        int rr = flat >> 4, c4 = (flat & 15) * 4;
        size_t g = (size_t)(rb + rr) * 64 + c4;
        floatx4 xv = *(const floatx4*)&x[g];
        floatx4 pv = *(const floatx4*)&p[g];
        half4v h;
        h[0] = (_Float16)(xv.x + pv.x); h[1] = (_Float16)(xv.y + pv.y);
        h[2] = (_Float16)(xv.z + pv.z); h[3] = (_Float16)(xv.w + pv.w);
        *(half4v*)&A_s[rr * 72 + c4] = h;
    }
    __syncthreads();

    const int w = tid >> 6, lane = tid & 63, m = lane & 15, qd = lane >> 4;
    const floatx4 fz = {0.f, 0.f, 0.f, 0.f};
    floatx4 acc[2][4];
    #pragma unroll
    for (int rt = 0; rt < 2; rt++)
        #pragma unroll
        for (int ct = 0; ct < 4; ct++) acc[rt][ct] = fz;

    #pragma unroll
    for (int kc = 0; kc < 2; ++kc) {
        const int k0 = kc * 32 + qd * 8;
        half8 b[4];
        #pragma unroll
        for (int ct = 0; ct < 4; ++ct)
            b[ct] = *(const half8*)&WT_s[(ct * 16 + m) * 72 + k0];
        #pragma unroll
        for (int rt = 0; rt < 2; ++rt) {
            half8 a = *(const half8*)&A_s[(w * 32 + rt * 16 + m) * 72 + k0];
            #pragma unroll
            for (int ct = 0; ct < 4; ++ct)
                acc[rt][ct] = __builtin_amdgcn_mfma_f32_16x16x32_f16(a, b[ct], acc[rt][ct], 0, 0, 0);
        }
    }
    #pragma unroll
    for (int rt = 0; rt < 2; rt++)
        #pragma unroll
        for (int ct = 0; ct < 4; ct++) {
            const int col = ct * 16 + m;
            const float bb = bqk[col];
            #pragma unroll
            for (int rg = 0; rg < 4; ++rg) {
                const int row = w * 32 + rt * 16 + qd * 4 + rg;
                A_s[row * 72 + col] = (_Float16)(acc[rt][ct][rg] + bb);
            }
        }
    __syncthreads();
    #pragma unroll
    for (int j = 0; j < 4; ++j) {
        int ch = tid + j * 256;
        int rr = ch >> 3, off = (ch & 7) * 8;
        *(half8*)&o[(size_t)(rb + rr) * 64 + off] = *(const half8*)&A_s[rr * 72 + off];
    }
}

// ---------------- persistent fused edge-MLP + softmax + aggregate ----------------
// Round-0 proven structure: 2 waves/EU, 256-VGPR budget, no spill (verify: WRITE_SIZE ~9 MB).
// Changes vs round 0 (all register-neutral):
//  - idx/mask prefetch at tile top (idxn(t) dead there); kpr(t+1) gathered after pair-1's Wg1
//    (its last reader) -> gather->use distance ~2k cyc instead of ~400.
//  - bg2 dropped (softmax-invariant); bv folded post-norm (sum attn == 1); Wg2 pre-scaled by
//    log2e so softmax uses raw v_exp_f32; fused s/weighted-sum shuffle reduce + v_rcp.
__global__ __launch_bounds__(256) __attribute__((amdgpu_waves_per_eu(2, 2)))
void cross_attn(const float* __restrict__ value, const unsigned short* __restrict__ mask_packed,
                const int* __restrict__ idx,
                const _Float16* __restrict__ qp_h, const _Float16* __restrict__ kp_h,
                const _Float16* __restrict__ w4,
                const float* __restrict__ bg1, const float* __restrict__ bv,
                _Float16* __restrict__ res_g)
{
    __shared__ __align__(16) _Float16 W3_s[3 * 64 * 72];  // Wg1T, Wg2T, WvT
    __shared__ __align__(16) _Float16 H_s[256 * 72];      // wave-private 64-row regions

    const int tid = threadIdx.x, w = tid >> 6, lane = tid & 63, m = lane & 15, qd = (lane >> 4) & 3;
    const int tile0 = blockIdx.x * TPB;

    for (int ch = tid; ch < 1728; ch += 256)
        *(half8*)&W3_s[ch * 8] = *(const half8*)&w4[ch * 8];

    float bg1v[4];
    #pragma unroll
    for (int ct = 0; ct < 4; ct++) bg1v[ct] = bg1[ct * 16 + m];
    const float bvsel = bv[lane];   // res col == lane; sum(attn)==1 -> bv adds post-norm

    // ---- prologue: tile-0 idx/mask/qp/value loads + tile-0 kp gather ----
    int idxn[4]; unsigned mpr[4];
    half8 qpr[4][2], kpr[4][2];
    floatx4 vraw[16];
    {
        const int q0 = tile0 * 16;
        #pragma unroll
        for (int rt = 0; rt < 4; ++rt) {
            const int qrow = q0 + w * 4 + rt;
            idxn[rt] = idx[qrow * KNB + m];
            mpr[rt]  = mask_packed[qrow];
            #pragma unroll
            for (int kc = 0; kc < 2; ++kc)
                qpr[rt][kc] = *(const half8*)&qp_h[(size_t)qrow * 64 + kc * 32 + qd * 8];
            #pragma unroll
            for (int kc = 0; kc < 2; ++kc) {
                const float* vr = value + ((size_t)qrow * KNB + m) * 64 + kc * 32 + qd * 8;
                vraw[(rt * 2 + kc) * 2 + 0] = *(const floatx4*)vr;
                vraw[(rt * 2 + kc) * 2 + 1] = *(const floatx4*)(vr + 4);
            }
        }
        #pragma unroll
        for (int rt = 0; rt < 4; ++rt)
            #pragma unroll
            for (int kc = 0; kc < 2; ++kc)
                kpr[rt][kc] = *(const half8*)&kp_h[(size_t)idxn[rt] * 64 + kc * 32 + qd * 8];
    }
    __syncthreads();   // weights ready; ONLY barrier

    const _Float16* Wg1T = W3_s;
    const _Float16* Wg2T = W3_s + 4608;
    const _Float16* WvT  = W3_s + 2 * 4608;
    const floatx4 fz = {0.f, 0.f, 0.f, 0.f};

    for (int t = 0; t < TPB; ++t) {
        const int q0t = (tile0 + t) * 16;
        const bool more = (t + 1 < TPB);

        unsigned mcur[4];
        #pragma unroll
        for (int rt = 0; rt < 4; ++rt) mcur[rt] = mpr[rt];

        // ---- tile top: idxn(t)/mpr(t) are dead (kpr(t) gathered last tile) -> prefetch t+1 ----
        if (more) {
            const int q0n = q0t + 16;
            #pragma unroll
            for (int rt = 0; rt < 4; ++rt) {
                const int qrow = q0n + w * 4 + rt;
                idxn[rt] = idx[qrow * KNB + m];
                mpr[rt]  = mask_packed[qrow];
            }
        }

        // ---- process queries in pairs (register diet: 32-reg accumulator sets) ----
        #pragma unroll
        for (int pr = 0; pr < 2; ++pr) {
            const int r0 = pr * 2;

            // value(t) frags for this pair (waits on rolling buffer loads)
            half8 vfrag[2][2];
            #pragma unroll
            for (int rr = 0; rr < 2; ++rr)
                #pragma unroll
                for (int kc = 0; kc < 2; ++kc) {
                    floatx4 x0 = vraw[((r0 + rr) * 2 + kc) * 2 + 0];
                    floatx4 x1 = vraw[((r0 + rr) * 2 + kc) * 2 + 1];
                    half8 a;
                    #pragma unroll
                    for (int j = 0; j < 4; ++j) { a[j] = (_Float16)x0[j]; a[4 + j] = (_Float16)x1[j]; }
                    vfrag[rr][kc] = a;
                }

            // v = value @ Wv for pair (no bias; bv folded post-norm)
            floatx4 accv2[2][4];
            #pragma unroll
            for (int rr = 0; rr < 2; ++rr)
                #pragma unroll
                for (int ct = 0; ct < 4; ++ct) accv2[rr][ct] = fz;
            #pragma unroll
            for (int kc = 0; kc < 2; ++kc) {
                const int k0 = kc * 32 + qd * 8;
                half8 b[4];
                #pragma unroll
                for (int ct = 0; ct < 4; ++ct)
                    b[ct] = *(const half8*)&WvT[(ct * 16 + m) * 72 + k0];
                #pragma unroll
                for (int rr = 0; rr < 2; ++rr)
                    #pragma unroll
                    for (int ct = 0; ct < 4; ++ct)
                        accv2[rr][ct] = __builtin_amdgcn_mfma_f32_16x16x32_f16(vfrag[rr][kc], b[ct], accv2[rr][ct], 0, 0, 0);
            }

            // refill this pair's vraw slots with tile t+1 (in-flight ~ one full tile)
            if (more) {
                const int q0n = q0t + 16;
                #pragma unroll
                for (int rr = 0; rr < 2; ++rr) {
                    const int qrow = q0n + w * 4 + r0 + rr;
                    #pragma unroll
                    for (int kc = 0; kc < 2; ++kc) {
                        const float* vr = value + ((size_t)qrow * KNB + m) * 64 + kc * 32 + qd * 8;
                        vraw[((r0 + rr) * 2 + kc) * 2 + 0] = *(const floatx4*)vr;
                        vraw[((r0 + rr) * 2 + kc) * 2 + 1] = *(const floatx4*)(vr + 4);
                    }
                }
            }

            // h = relu(d @ Wg1 + b) for pair, d-frags in registers (kpr gathered ~a tile ago)
            floatx4 acch2[2][4];
            #pragma unroll
            for (int rr = 0; rr < 2; ++rr)
                #pragma unroll
                for (int ct = 0; ct < 4; ++ct) acch2[rr][ct] = fz;
            #pragma unroll
            for (int kc = 0; kc < 2; ++kc) {
                const int k0 = kc * 32 + qd * 8;
                half8 b[4];
                #pragma unroll
                for (int ct = 0; ct < 4; ++ct)
                    b[ct] = *(const half8*)&Wg1T[(ct * 16 + m) * 72 + k0];
                #pragma unroll
                for (int rr = 0; rr < 2; ++rr) {
                    half8 a = qpr[r0 + rr][kc] - kpr[r0 + rr][kc];
                    #pragma unroll
                    for (int ct = 0; ct < 4; ++ct)
                        acch2[rr][ct] = __builtin_amdgcn_mfma_f32_16x16x32_f16(a, b[ct], acch2[rr][ct], 0, 0, 0);
                }
            }

            // pair-1 Wg1 was the last reader of kpr(t); idxn already holds t+1 -> gather kpr(t+1)
            if (pr == 1 && more) {
                #pragma unroll
                for (int rt = 0; rt < 4; ++rt)
                    #pragma unroll
                    for (int kc = 0; kc < 2; ++kc)
                        kpr[rt][kc] = *(const half8*)&kp_h[(size_t)idxn[rt] * 64 + kc * 32 + qd * 8];
            }

            // h -> wave-private LDS
            #pragma unroll
            for (int rr = 0; rr < 2; ++rr)
                #pragma unroll
                for (int ct = 0; ct < 4; ++ct) {
                    const int col = ct * 16 + m;
                    #pragma unroll
                    for (int rg = 0; rg < 4; ++rg) {
                        const int row = w * 64 + (r0 + rr) * 16 + qd * 4 + rg;
                        float h = acch2[rr][ct][rg] + bg1v[ct];
                        H_s[row * 72 + col] = (_Float16)fmaxf(h, 0.f);
                    }
                }
            __asm__ volatile("s_waitcnt lgkmcnt(0)" ::: "memory");

            // e = h @ Wg2 for pair (Wg2 pre-scaled by log2e; bg2 dropped: softmax-invariant)
            floatx4 acce2[2][4];
            #pragma unroll
            for (int rr = 0; rr < 2; ++rr)
                #pragma unroll
                for (int ct = 0; ct < 4; ++ct) acce2[rr][ct] = fz;
            #pragma unroll
            for (int kc = 0; kc < 2; ++kc) {
                const int k0 = kc * 32 + qd * 8;
                half8 b[4];
                #pragma unroll
                for (int ct = 0; ct < 4; ++ct)
                    b[ct] = *(const half8*)&Wg2T[(ct * 16 + m) * 72 + k0];
                #pragma unroll
                for (int rr = 0; rr < 2; ++rr) {
                    half8 a = *(const half8*)&H_s[(w * 64 + (r0 + rr) * 16 + m) * 72 + k0];
                    #pragma unroll
                    for (int ct = 0; ct < 4; ++ct)
                        acce2[rr][ct] = __builtin_amdgcn_mfma_f32_16x16x32_f16(a, b[ct], acce2[rr][ct], 0, 0, 0);
                }
            }

            // softmax over 16 neighbors + aggregate + res store (f16); fused s/weighted reduce
            #pragma unroll
            for (int rr = 0; rr < 2; ++rr) {
                const int rt = r0 + rr;
                float tca[4];
                #pragma unroll
                for (int ct = 0; ct < 4; ++ct) {
                    float ev[4];
                    #pragma unroll
                    for (int rg = 0; rg < 4; ++rg) {
                        float e = acce2[rr][ct][rg];
                        ev[rg] = ((mcur[rt] >> (qd * 4 + rg)) & 1u) ? -1e12f : e;
                    }
                    float mx = fmaxf(fmaxf(ev[0], ev[1]), fmaxf(ev[2], ev[3]));
                    mx = fmaxf(mx, __shfl_xor(mx, 16));
                    mx = fmaxf(mx, __shfl_xor(mx, 32));
                    float s = 0.f, ttu = 0.f;
                    #pragma unroll
                    for (int rg = 0; rg < 4; ++rg) {
                        float p = EXP2F(ev[rg] - mx);   // base-2: log2e folded into Wg2
                        s += p; ttu += p * accv2[rr][ct][rg];
                    }
                    s   += __shfl_xor(s, 16);   ttu += __shfl_xor(ttu, 16);
                    s   += __shfl_xor(s, 32);   ttu += __shfl_xor(ttu, 32);
                    tca[ct] = ttu * __builtin_amdgcn_rcpf(s);
                }
                float tsel = (qd == 0) ? tca[0] : (qd == 1) ? tca[1] : (qd == 2) ? tca[2] : tca[3];
                res_g[(size_t)(q0t + w * 4 + rt) * 64 + lane] = (_Float16)(tsel + bvsel);
            }
        }

        // after pair 1: prefetch next tile's qp
        if (more) {
            const int q0n = q0t + 16;
            #pragma unroll
            for (int rt = 0; rt < 4; ++rt) {
                const int qrow = q0n + w * 4 + rt;
                #pragma unroll
                for (int kc = 0; kc < 2; ++kc)
                    qpr[rt][kc] = *(const half8*)&qp_h[(size_t)qrow * 64 + kc * 32 + qd * 8];
            }
        }
    }
}

// ---------------- out = res @ Wt + bt ----------------
__global__ __launch_bounds__(256, 4)
void out_proj(const _Float16* __restrict__ res_g, const _Float16* __restrict__ w4,
              const float* __restrict__ bt, float* __restrict__ out)
{
    __shared__ __align__(16) _Float16 WtT_s[64 * 72];
    const int tid = threadIdx.x;
    const _Float16* WtT_g = w4 + 3 * 4608;
    for (int ch = tid; ch < 576; ch += 256)
        *(half8*)&WtT_s[ch * 8] = *(const half8*)&WtT_g[ch * 8];
    __syncthreads();

    const int w = tid >> 6, lane = tid & 63, m = lane & 15, qd = lane >> 4;
    const int rb = blockIdx.x * 256;
    const floatx4 fz = {0.f, 0.f, 0.f, 0.f};
    float btv[4];
    #pragma unroll
    for (int ct = 0; ct < 4; ++ct) btv[ct] = bt[ct * 16 + m];

    #pragma unroll
    for (int rt = 0; rt < 4; ++rt) {
        floatx4 acc[4] = {fz, fz, fz, fz};
        #pragma unroll
        for (int kc = 0; kc < 2; ++kc) {
            const int k0 = kc * 32 + qd * 8;
            half8 a = *(const half8*)&res_g[(size_t)(rb + w * 64 + rt * 16 + m) * 64 + k0];
            half8 b[4];
            #pragma unroll
            for (int ct = 0; ct < 4; ++ct)
                b[ct] = *(const half8*)&WtT_s[(ct * 16 + m) * 72 + k0];
            #pragma unroll
            for (int ct = 0; ct < 4; ++ct)
                acc[ct] = __builtin_amdgcn_mfma_f32_16x16x32_f16(a, b[ct], acc[ct], 0, 0, 0);
        }
        #pragma unroll
        for (int ct = 0; ct < 4; ++ct) {
            #pragma unroll
            for (int rg = 0; rg < 4; ++rg)
                out[(size_t)(rb + w * 64 + rt * 16 + qd * 4 + rg) * 64 + ct * 16 + m] = acc[ct][rg] + btv[ct];
        }
    }
}

extern "C" void kernel_launch(void* const* d_in, const int* in_sizes, int n_in,
                              void* d_out, int out_size, void* d_ws, size_t ws_size,
                              hipStream_t stream) {
    const float* q     = (const float*)d_in[0];
    const float* k     = (const float*)d_in[1];
    const float* value = (const float*)d_in[2];
    const float* q_pos = (const float*)d_in[3];
    const float* k_pos = (const float*)d_in[4];
    const unsigned char* mask = (const unsigned char*)d_in[5];
    const int* knn     = (const int*)d_in[6];
    // d_in[7] = k_num scalar (16)
    const float* Wqk = (const float*)d_in[8];
    const float* bqk = (const float*)d_in[9];
    const float* Wv  = (const float*)d_in[10];
    const float* bv  = (const float*)d_in[11];
    const float* Wg1 = (const float*)d_in[12];
    const float* bg1 = (const float*)d_in[13];
    const float* Wg2 = (const float*)d_in[14];
    const float* bg2 = (const float*)d_in[15];
    const float* Wt  = (const float*)d_in[16];
    const float* bt  = (const float*)d_in[17];
    float* out = (float*)d_out;
    (void)bg2;   // softmax-invariant along neighbor axis: dropped

    _Float16* qp_h  = (_Float16*)d_ws;
    _Float16* kp_h  = qp_h + (size_t)MQ * CCH;
    _Float16* res_g = kp_h + (size_t)NKEY * CCH;
    _Float16* w4    = res_g + (size_t)MQ * CCH;
    unsigned short* mask_packed = (unsigned short*)(w4 + 4 * 64 * 72);
    int* mflag = (int*)(mask_packed + MQ);
    const int* idx = knn + (size_t)MQ * KNB;   // row 1 of knearest_idx

    detect_mask<<<1, 256, 0, stream>>>(mask, mflag);
    proj_prep<<<1089, 256, 0, stream>>>(q, q_pos, k, k_pos, Wqk, bqk,
                                        Wg1, Wg2, Wv, Wt, mask, mflag,
                                        qp_h, kp_h, w4, mask_packed);
    cross_attn<<<MQ / (16 * TPB), 256, 0, stream>>>(value, mask_packed, idx, qp_h, kp_h, w4,
                                                    bg1, bv, res_g);
    out_proj<<<MQ / 256, 256, 0, stream>>>(res_g, w4, bt, out);
}